// Round 2
// 283.913 us; speedup vs baseline: 1.0138x; 1.0138x over previous
//
#include <hip/hip_runtime.h>
#include <math.h>

// Problem constants (fixed instance per reference setup_inputs)
#define NB 2
#define C  256
#define H  200
#define W  304
#define HW (H * W)                       // 60800 (divisible by 64)
#define PH 7
#define PW 7
#define CELLS (PH * PW)                  // 49
#define SPATIAL_SCALE 0.25f
#define NHWC_ELEMS ((size_t)NB * H * W * C)
#define NHWC_BYTES (NHWC_ELEMS * sizeof(float))   // 124,518,400

// clang native vector type: required for __builtin_nontemporal_load
// (HIP's float4 is a class and is rejected by the builtin).
typedef float f32x4 __attribute__((ext_vector_type(4)));

// R7 gather geometry: each block handles ONE channel-half (128 ch) of one ROI.
#define CH_HALF   (C / 2)                // 128 channels per block
#define SH_STRIDE 130                    // floats; 130%32==2 -> <=2-way bank conflict
                                         // on the reorder read; 8B-aligned float2 rows
#define OUT_HALF  (CH_HALF * CELLS)      // 6272 floats per block

// ---------------------------------------------------------------------------
// Kernel A (R7): NCHW -> NHWC transpose, 64x64 tile, float4 both directions.
// NCHW source is read exactly once and never again -> nontemporal loads so
// the dead lines don't evict the NHWC tensor from the 256MB LLC (that
// eviction is the gather's 2.1x over-fetch). NHWC stores stay cached.
// Exact grid: (60800/64, 256/64, 2) = (950, 4, 2), block (16,16). No guards.
// ---------------------------------------------------------------------------
__global__ __launch_bounds__(256) void nchw_to_nhwc(
    const float* __restrict__ in, float* __restrict__ out)
{
    __shared__ float tile[64][65];       // [channel][spatial]
    const int n  = blockIdx.z;
    const int s0 = blockIdx.x * 64;      // spatial tile origin
    const int c0 = blockIdx.y * 64;      // channel tile origin
    const int tx = threadIdx.x;          // 0..15
    const int ty = threadIdx.y;          // 0..15

    const float* __restrict__ src = in  + (size_t)n * C  * HW;
    float*       __restrict__ dst = out + (size_t)n * HW * C;

#pragma unroll
    for (int i = 0; i < 4; ++i) {
        const int c = ty + i * 16;       // local channel row
        const f32x4 v = __builtin_nontemporal_load(
            (const f32x4*)(src + (size_t)(c0 + c) * HW + s0) + tx);
        tile[c][tx * 4 + 0] = v.x;
        tile[c][tx * 4 + 1] = v.y;
        tile[c][tx * 4 + 2] = v.z;
        tile[c][tx * 4 + 3] = v.w;
    }
    __syncthreads();
#pragma unroll
    for (int i = 0; i < 4; ++i) {
        const int s = ty + i * 16;       // local spatial row
        float4 v;
        v.x = tile[tx * 4 + 0][s];
        v.y = tile[tx * 4 + 1][s];
        v.z = tile[tx * 4 + 2][s];
        v.w = tile[tx * 4 + 3][s];
        *((float4*)(dst + (size_t)(s0 + s) * C + c0) + tx) = v;   // cached store
    }
}

// ---------------------------------------------------------------------------
// Kernel B (R7): grid (R, 2) — each block does 128 channels of one ROI.
// 64 lanes x float2 = 128 channels per wave-load (512B contiguous, coalesced);
// 4 waves split the 49 cells in PAIRS (R6 scheme kept: ~32 loads in flight).
// LDS 25.5KB -> 6 blocks/CU (was 50.9KB -> 3); __launch_bounds__(256,6) caps
// VGPR at 85 (float2 halves in-flight data regs vs the 88-VGPR float4 R6).
// Output stores are nontemporal: never re-read, keep them out of the LLC.
// ---------------------------------------------------------------------------
__device__ __forceinline__ void cell_prep(
    int cell, float start_h, float start_w, float bin_h, float bin_w,
    float ct, float st, float cx, float cy,
    int* __restrict__ q, float* __restrict__ wgt)
{
    const int ph = cell / 7;
    const int pw = cell - ph * 7;
#pragma unroll
    for (int s = 0; s < 4; ++s) {
        const int iy = s >> 1, ix = s & 1;
        const float yy = start_h + (float)ph * bin_h
                       + ((float)iy + 0.5f) * bin_h * 0.5f;
        const float xx = start_w + (float)pw * bin_w
                       + ((float)ix + 0.5f) * bin_w * 0.5f;
        const float y = yy * ct - xx * st + cy;
        const float x = yy * st + xx * ct + cx;

        // validity on UNclipped coords (reference semantics); fold /4 in
        const bool valid = (y >= -1.0f) && (y <= (float)H)
                        && (x >= -1.0f) && (x <= (float)W);
        const float wv = valid ? 0.25f : 0.0f;

        const float yc = fminf(fmaxf(y, 0.0f), (float)(H - 1));
        const float xc = fminf(fmaxf(x, 0.0f), (float)(W - 1));
        const int yl = (int)floorf(yc);
        const int xl = (int)floorf(xc);
        const int yh = min(yl + 1, H - 1);
        const int xh = min(xl + 1, W - 1);
        const float ly = yc - (float)yl;
        const float lx = xc - (float)xl;
        const float hy = 1.0f - ly;
        const float hx = 1.0f - lx;

        q[s * 4 + 0] = (yl * W + xl) * CH_HALF;   // float2 units: pix * (C/2)
        q[s * 4 + 1] = (yl * W + xh) * CH_HALF;
        q[s * 4 + 2] = (yh * W + xl) * CH_HALF;
        q[s * 4 + 3] = (yh * W + xh) * CH_HALF;
        wgt[s * 4 + 0] = hy * hx * wv;
        wgt[s * 4 + 1] = hy * lx * wv;
        wgt[s * 4 + 2] = ly * hx * wv;
        wgt[s * 4 + 3] = ly * lx * wv;
    }
}

__global__ __launch_bounds__(256, 6) void roi_gather_nhwc(
    const float* __restrict__ nhwc, const float* __restrict__ rois,
    float* __restrict__ out)
{
    __shared__ float sh[CELLS * SH_STRIDE];   // 25480 B -> 6 blocks/CU
    const int t    = threadIdx.x;
    const int lane = t & 63;
    const int w    = t >> 6;          // wave id 0..3
    const int r    = blockIdx.x;
    const int hh   = blockIdx.y;      // channel half 0/1

    const float* rr = rois + (size_t)r * 6;
    const int   b   = (int)rr[0];
    const float cx  = rr[1] * SPATIAL_SCALE - 0.5f;
    const float cy  = rr[2] * SPATIAL_SCALE - 0.5f;
    const float rw  = rr[3] * SPATIAL_SCALE;
    const float rh  = rr[4] * SPATIAL_SCALE;
    const float th  = rr[5] * (float)(M_PI / 180.0);
    float st, ct;
    sincosf(th, &st, &ct);

    const float bin_h   = rh * (1.0f / PH);
    const float bin_w   = rw * (1.0f / PW);
    const float start_h = -rh * 0.5f;
    const float start_w = -rw * 0.5f;

    // base2 + pix*(C/2) addresses channels [hh*128+2*lane, +2) of pixel pix
    const float2* __restrict__ base2 =
        (const float2*)nhwc + (size_t)b * HW * (C / 2) + hh * 64 + lane;

    int cell;
    for (cell = w; cell + 4 < CELLS; cell += 8) {
        int   qA[16], qB[16];
        float wA[16], wB[16];
        cell_prep(cell,     start_h, start_w, bin_h, bin_w, ct, st, cx, cy, qA, wA);
        cell_prep(cell + 4, start_h, start_w, bin_h, bin_w, ct, st, cx, cy, qB, wB);

        float2 vA[16], vB[16];
#pragma unroll
        for (int i = 0; i < 16; ++i) vA[i] = base2[qA[i]];
#pragma unroll
        for (int i = 0; i < 16; ++i) vB[i] = base2[qB[i]];

        float2 accA = make_float2(0.f, 0.f);
        float2 accB = make_float2(0.f, 0.f);
#pragma unroll
        for (int i = 0; i < 16; ++i) {
            accA.x = fmaf(wA[i], vA[i].x, accA.x);
            accA.y = fmaf(wA[i], vA[i].y, accA.y);
        }
#pragma unroll
        for (int i = 0; i < 16; ++i) {
            accB.x = fmaf(wB[i], vB[i].x, accB.x);
            accB.y = fmaf(wB[i], vB[i].y, accB.y);
        }
        *(float2*)&sh[cell       * SH_STRIDE + lane * 2] = accA;
        *(float2*)&sh[(cell + 4) * SH_STRIDE + lane * 2] = accB;
    }
    if (cell < CELLS) {               // leftover (wave 0: cell 48)
        int   qA[16];
        float wA[16];
        cell_prep(cell, start_h, start_w, bin_h, bin_w, ct, st, cx, cy, qA, wA);
        float2 vA[16];
#pragma unroll
        for (int i = 0; i < 16; ++i) vA[i] = base2[qA[i]];
        float2 accA = make_float2(0.f, 0.f);
#pragma unroll
        for (int i = 0; i < 16; ++i) {
            accA.x = fmaf(wA[i], vA[i].x, accA.x);
            accA.y = fmaf(wA[i], vA[i].y, accA.y);
        }
        *(float2*)&sh[cell * SH_STRIDE + lane * 2] = accA;
    }

    __syncthreads();

    // 6272 = 128*49 floats: 24.5 coalesced 1KB wave stores (nontemporal).
    const size_t ob = (size_t)r * (C * CELLS) + (size_t)hh * OUT_HALF;
#pragma unroll
    for (int k = 0; k < 25; ++k) {
        const int f = k * 256 + t;            // flat index = c_local*49 + cell
        if (f < OUT_HALF) {
            const int c     = f / 49;
            const int cell2 = f - c * 49;
            __builtin_nontemporal_store(sh[cell2 * SH_STRIDE + c], &out[ob + f]);
        }
    }
}

// ---------------------------------------------------------------------------
// Fallback (proven round-1 kernel): used only if ws_size can't hold NHWC.
// ---------------------------------------------------------------------------
__global__ __launch_bounds__(256) void roi_align_direct(
    const float* __restrict__ inp, const float* __restrict__ rois,
    float* __restrict__ out)
{
    const int r   = blockIdx.x;
    const int idx = blockIdx.y * 256 + threadIdx.x;   // < 12544
    const int c    = idx / 49;
    const int cell = idx - c * 49;
    const int ph   = cell / 7;
    const int pw   = cell - ph * 7;

    const float* rr = rois + (size_t)r * 6;
    const int   b   = (int)rr[0];
    const float cx  = rr[1] * SPATIAL_SCALE - 0.5f;
    const float cy  = rr[2] * SPATIAL_SCALE - 0.5f;
    const float rw  = rr[3] * SPATIAL_SCALE;
    const float rh  = rr[4] * SPATIAL_SCALE;
    const float th  = rr[5] * (float)(M_PI / 180.0);
    float st, ct;
    sincosf(th, &st, &ct);

    const float bin_h   = rh * (1.0f / PH);
    const float bin_w   = rw * (1.0f / PW);
    const float start_h = -rh * 0.5f;
    const float start_w = -rw * 0.5f;

    const float* __restrict__ plane = inp + (size_t)(b * C + c) * HW;

    float acc = 0.0f;
#pragma unroll
    for (int s = 0; s < 4; ++s) {
        const int iy = s >> 1, ix = s & 1;
        const float yy = start_h + (float)ph * bin_h
                       + ((float)iy + 0.5f) * bin_h * 0.5f;
        const float xx = start_w + (float)pw * bin_w
                       + ((float)ix + 0.5f) * bin_w * 0.5f;
        const float y = yy * ct - xx * st + cy;
        const float x = yy * st + xx * ct + cx;

        const bool valid = (y >= -1.0f) && (y <= (float)H)
                        && (x >= -1.0f) && (x <= (float)W);
        const float wv = valid ? 0.25f : 0.0f;

        const float yc = fminf(fmaxf(y, 0.0f), (float)(H - 1));
        const float xc = fminf(fmaxf(x, 0.0f), (float)(W - 1));
        const int yl = (int)floorf(yc);
        const int xl = (int)floorf(xc);
        const int yh = min(yl + 1, H - 1);
        const int xh = min(xl + 1, W - 1);
        const float ly = yc - (float)yl;
        const float lx = xc - (float)xl;
        const float hy = 1.0f - ly;
        const float hx = 1.0f - lx;

        acc += wv * (hy * (hx * plane[yl * W + xl] + lx * plane[yl * W + xh])
                   + ly * (hx * plane[yh * W + xl] + lx * plane[yh * W + xh]));
    }

    out[(size_t)r * (C * PH * PW) + idx] = acc;
}

extern "C" void kernel_launch(void* const* d_in, const int* in_sizes, int n_in,
                              void* d_out, int out_size, void* d_ws, size_t ws_size,
                              hipStream_t stream) {
    const float* inp  = (const float*)d_in[0];
    const float* rois = (const float*)d_in[1];
    float* out = (float*)d_out;
    const int R = in_sizes[1] / 6;            // 1000

    if (ws_size >= NHWC_BYTES) {
        float* nhwc = (float*)d_ws;
        dim3 gA(HW / 64, C / 64, NB);         // (950, 4, 2) — exact
        dim3 bA(16, 16, 1);
        nchw_to_nhwc<<<gA, bA, 0, stream>>>(inp, nhwc);

        roi_gather_nhwc<<<dim3(R, 2), 256, 0, stream>>>(nhwc, rois, out);
    } else {
        dim3 grid(R, (C * PH * PW) / 256);    // (1000, 49) — exact
        roi_align_direct<<<grid, 256, 0, stream>>>(inp, rois, out);
    }
}